// Round 8
// baseline (326.314 us; speedup 1.0000x reference)
//
#include <hip/hip_runtime.h>
#include <math.h>

constexpr float DXC    = 3.125f;                              // 400/128
constexpr float INV_DX = 0.32f;                               // 1/3.125
constexpr float XMINC  = -200.0f;
constexpr float KW2    = 9.0f * 3.14159265358979323846f;      // cutoff^2 (mm^2)
constexpr float DXC2   = DXC * DXC;                           // 9.765625
constexpr float KW2C   = KW2 / DXC2;                          // cutoff^2 in cell^2
constexpr float NEGL2C = -(2.0f / KW2) * 1.4426950408889634f * DXC2; // exp2 scale (cell^2)
constexpr float WOFF   = 1.7983f;                             // window anchor offset

constexpr int TPB    = 1024;
constexpr int LPB    = 1024;
constexpr int KSPLIT = 4;
constexpr int KCH    = 128 / KSPLIT;
constexpr int QTAB   = 1024;   // table bins over s in [0,4)

__device__ inline unsigned bf16_rn(float x) {
    unsigned u = __float_as_uint(x);
    return (u + 0x7fffu + ((u >> 16) & 1u)) >> 16;
}
__device__ inline unsigned pk_bf16(float x, float y) {
    return bf16_rn(x) | (bf16_rn(y) << 16);
}
__device__ inline float uaf(unsigned u) { return __uint_as_float(u); }

// ================= prep kernels =================
// V0[k][i][j]=img[k][i][j]; V1[k][i][j]=img[i][k][j]; V2[k][i][j]=img[i][j][k]
// S* = V* shifted by one bf16 within rows (flat +1; bleed indices never read).
__global__ __launch_bounds__(256) void prep2_kernel(const float* __restrict__ img,
                                                    ushort* __restrict__ V0, ushort* __restrict__ V1,
                                                    ushort* __restrict__ V2, ushort* __restrict__ S0,
                                                    ushort* __restrict__ S1, ushort* __restrict__ S2) {
    int o = blockIdx.x * 256 + threadIdx.x;           // o = (a,b,c)
    int c = o & 127, b = (o >> 7) & 127, a = o >> 14;
    float x  = img[o];
    float xn = (c < 127) ? img[o + 1] : 0.0f;
    unsigned h  = bf16_rn(x);
    unsigned hn = bf16_rn(xn);
    V0[o] = (ushort)h;
    S0[o] = (ushort)((c < 127) ? hn : 0u);
    int p1 = (b << 14) | (a << 7) | c;
    V1[p1] = (ushort)h;
    S1[p1] = (ushort)((c < 127) ? hn : 0u);
    // o = (k,i,j) for V2: k=a, i=b, j=c
    V2[o] = (ushort)bf16_rn(img[(b << 14) | (c << 7) | a]);
    S2[o] = (ushort)((c < 127) ? bf16_rn(img[(b << 14) | ((c + 1) << 7) | a]) : 0u);
}

__global__ __launch_bounds__(256) void prep_kernel(const float* __restrict__ img,
                                                   ushort* __restrict__ V0,
                                                   ushort* __restrict__ V1,
                                                   ushort* __restrict__ V2) {
    int o = blockIdx.x * 256 + threadIdx.x;
    float x = img[o];
    unsigned h = bf16_rn(x);
    V0[o] = (ushort)h;
    int c = o & 127, b = (o >> 7) & 127, a = o >> 14;
    V1[(b << 14) | (a << 7) | c] = (ushort)h;
    int j = o & 127, i = (o >> 7) & 127, k = o >> 14;
    V2[o] = (ushort)bf16_rn(img[(i << 14) | (j << 7) | k]);
}

__global__ __launch_bounds__(1024) void zero_kernel(float* __restrict__ out, int m) {
    int i = blockIdx.x * 1024 + threadIdx.x;
    if (i < m) out[i] = 0.0f;
}

// ================= staging =================
__device__ inline void stage_one(const ushort* __restrict__ V, int k, int tid, void* dst) {
    const char* src = (const char*)(V + ((size_t)k << 14));
    char* d = (char*)dst;
    int wbase = (tid >> 6) << 10;
    int lane16 = (tid & 63) << 4;
#pragma unroll
    for (int c = 0; c < 2; ++c) {
        int half = c << 14;
        __builtin_amdgcn_global_load_lds(
            (__attribute__((address_space(1))) void*)(const_cast<char*>(src + half + wbase + lane16)),
            (__attribute__((address_space(3))) void*)(d + half + wbase),
            16, 0, 0);
    }
}

// ================= v8: shifted-pair single-buffer kernel =================
struct WIN {
    float eb[4], ea[4], b[4], t[4];
    const uint* base;
    int adw;
};

__device__ inline WIN make_window(float u, float v, const uint2* wt,
                                  const uint* A, const uint* B) {
    WIN w;
    float e0f = fminf(fmaxf(floorf(v - WOFF), 0.0f), 124.0f);
    int   e0  = (int)e0f;
    int   qv  = min((int)((v - e0f) * (QTAB / 4.0f)), QTAB - 1);
    uint2 tb = wt[qv];
    w.eb[0] = uaf(tb.x << 16); w.eb[1] = uaf(tb.x & 0xffff0000u);
    w.eb[2] = uaf(tb.y << 16); w.eb[3] = uaf(tb.y & 0xffff0000u);
    float db0 = e0f + 0.5f - v;
    w.b[0] = db0 * db0;
    float gb = fmaf(2.0f, db0, 1.0f);
    w.b[1] = w.b[0] + gb; float gb1 = gb + 2.0f;
    w.b[2] = w.b[1] + gb1;
    w.b[3] = w.b[2] + gb1 + 2.0f;

    float i0f = fminf(fmaxf(floorf(u - WOFF), 0.0f), 124.0f);
    int   i0c = (int)i0f;
    int   qu  = min((int)((u - i0f) * (QTAB / 4.0f)), QTAB - 1);
    uint2 ta = wt[qu];
    w.ea[0] = uaf(ta.x << 16); w.ea[1] = uaf(ta.x & 0xffff0000u);
    w.ea[2] = uaf(ta.y << 16); w.ea[3] = uaf(ta.y & 0xffff0000u);
    float da0 = i0f + 0.5f - u;
    float a0 = da0 * da0;
    float ga = fmaf(2.0f, da0, 1.0f);
    float a1 = a0 + ga; float ga1 = ga + 2.0f;
    float a2 = a1 + ga1;
    float a3 = a2 + ga1 + 2.0f;
    w.t[0] = KW2C - a0; w.t[1] = KW2C - a1; w.t[2] = KW2C - a2; w.t[3] = KW2C - a3;

    w.base = (e0 & 1) ? B : A;
    w.adw  = (i0c << 6) + (e0 >> 1);
    return w;
}

template <int AXIS>
__device__ void proj_axis8(uint* slA, uint* slB, uint2* wt,
                           const ushort* __restrict__ V, const ushort* __restrict__ S,
                           const float* __restrict__ lors,
                           float* __restrict__ out, int n, int blk, int ks)
{
    const int tid = threadIdx.x;
    const int lor = blk * LPB + tid;
    const bool active = lor < n;
    const int lorc = active ? lor : n - 1;

    const float* l = lors + (size_t)lorc * 6;
    float l0 = l[0], l1 = l[1], l2 = l[2], l3 = l[3], l4 = l[4], l5 = l[5];
    float p0x, p0y, p0z, p1x, p1y, p1z;
    if (AXIS == 0)      { p0x = l1; p0y = l2; p0z = l0; p1x = l4; p1y = l5; p1z = l3; }
    else if (AXIS == 1) { p0x = l0; p0y = l2; p0z = l1; p1x = l3; p1y = l5; p1z = l4; }
    else                { p0x = l0; p0y = l1; p0z = l2; p1x = l3; p1y = l4; p1z = l5; }

    float dvx = p1x - p0x, dvy = p1y - p0y, dvz = p1z - p0z;
    float L     = sqrtf(dvx * dvx + dvy * dvy + dvz * dvz);
    float pathL = DXC * L / fabsf(dvz);
    float invdz = 1.0f / dvz;

    float dux  = dvx * INV_DX, ux0 = (p0x - XMINC) * INV_DX;
    float dvyS = dvy * INV_DX, vy0 = (p0y - XMINC) * INV_DX;
    float tzs = invdz, tz0 = -p0z * invdz;

    const int k0 = ks * KCH, k1 = k0 + KCH;
    float dt = DXC * tzs;
    float cu = dux * dt, cv = dvyS * dt;
    float zc0 = fmaf((float)k0, DXC, XMINC + 0.5f * DXC);
    float t0  = fmaf(zc0, tzs, tz0);
    float u   = fmaf(t0, dux, ux0);
    float v   = fmaf(t0, dvyS, vy0);
    float acc = 0.0f;

    // prologue: stage slice k0 (A+B) and fill bf16 weight table
    stage_one(V, k0, tid, slA);
    stage_one(S, k0, tid, slB);
    {
        float s = ((float)tid + 0.5f) * (4.0f / (float)QTAB);
        float o0 = 0.5f - s, o1 = 1.5f - s, o2 = 2.5f - s, o3 = 3.5f - s;
        float e0 = exp2f(o0 * o0 * NEGL2C);
        float e1 = exp2f(o1 * o1 * NEGL2C);
        float e2 = exp2f(o2 * o2 * NEGL2C);
        float e3 = exp2f(o3 * o3 * NEGL2C);
        wt[tid] = make_uint2(pk_bf16(e0, e1), pk_bf16(e2, e3));
    }
    __syncthreads();   // table ready AND slice k0 DMA drained

    WIN w = make_window(u, v, wt, slA, slB);

    for (int k = k0; k < k1; ++k) {
#pragma unroll
        for (int r = 0; r < 4; ++r) {
            uint d0 = w.base[w.adw + (r << 6)];
            uint d1 = w.base[w.adw + (r << 6) + 1];
            float w0 = uaf(d0 << 16);
            float w1 = uaf(d0 & 0xffff0000u);
            float w2 = uaf(d1 << 16);
            float w3 = uaf(d1 & 0xffff0000u);
            float tr = w.t[r];
            float rs;
            rs = __fmul_rn((w.b[0] <= tr) ? w.eb[0] : 0.0f, w0);
            rs = fmaf((w.b[1] <= tr) ? w.eb[1] : 0.0f, w1, rs);
            rs = fmaf((w.b[2] <= tr) ? w.eb[2] : 0.0f, w2, rs);
            rs = fmaf((w.b[3] <= tr) ? w.eb[3] : 0.0f, w3, rs);
            acc = fmaf(w.ea[r], rs, acc);
        }

        if (k < k1 - 1) {
            float un = u + cu, vn = v + cv;
            __syncthreads();                 // everyone done reading slice k
            stage_one(V, k + 1, tid, slA);   // overwrite with slice k+1
            stage_one(S, k + 1, tid, slB);
            w = make_window(un, vn, wt, slA, slB);  // VALU+wtab only: overlaps DMA
            u = un; v = vn;
            __syncthreads();                 // DMA drained -> slice k+1 ready
        }
    }

    if (active) atomicAdd(out + lor, acc * pathL);
}

__global__ __launch_bounds__(TPB, 8) void proj_fused8(const ushort* __restrict__ V0,
                                                      const ushort* __restrict__ V1,
                                                      const ushort* __restrict__ V2,
                                                      const ushort* __restrict__ S0,
                                                      const ushort* __restrict__ S1,
                                                      const ushort* __restrict__ S2,
                                                      const float* __restrict__ xl,
                                                      const float* __restrict__ yl,
                                                      const float* __restrict__ zl,
                                                      float* __restrict__ out,
                                                      int n, int nblk)
{
    __shared__ uint  slA[8192];      // 32 KiB slice (aligned copy)
    __shared__ uint  slB[8192];      // 32 KiB slice (+1 bf16 shifted copy)
    __shared__ uint2 wt[QTAB];       // 8 KiB bf16 weight table
    int per = nblk * KSPLIT;
    int axis = blockIdx.x / per;
    int r = blockIdx.x - axis * per;
    int blk = r >> 2;
    int ks  = r & 3;
    if (axis == 0)      proj_axis8<0>(slA, slB, wt, V0, S0, xl, out, n, blk, ks);
    else if (axis == 1) proj_axis8<1>(slA, slB, wt, V1, S1, yl, out + n, n, blk, ks);
    else                proj_axis8<2>(slA, slB, wt, V2, S2, zl, out + 2 * (size_t)n, n, blk, ks);
}

// ================= v7 fallback (R7 kernel, unchanged) =================
template <int AXIS>
__device__ inline void stage_issue(const float* __restrict__ img, int k, int tid,
                                   float4 st[4]) {
#pragma unroll
    for (int c = 0; c < 4; ++c) {
        int f4 = tid + TPB * c;
        int fl = f4 << 2;
        if (AXIS == 2) {
            int i = fl >> 7, j = fl & 127;
            const float* p = img + (i << 14) + (j << 7) + k;
            st[c] = make_float4(p[0], p[128], p[256], p[384]);
        } else {
            int off;
            if (AXIS == 1) off = ((fl >> 7) << 14) | (k << 7) | (fl & 127);
            else           off = (k << 14) | fl;
            st[c] = *reinterpret_cast<const float4*>(img + off);
        }
    }
}

__device__ inline void stage_write(const float4 st[4], ushort* slb, int tid) {
    uint* w = reinterpret_cast<uint*>(slb);
#pragma unroll
    for (int c = 0; c < 4; ++c) {
        int f4 = tid + TPB * c;
        w[f4 * 2]     = pk_bf16(st[c].x, st[c].y);
        w[f4 * 2 + 1] = pk_bf16(st[c].z, st[c].w);
    }
}

template <int AXIS, bool PRE>
__device__ void proj_axis7(ushort (*sl)[16384], float4* wtab,
                           const ushort* __restrict__ V,
                           const float*  __restrict__ imgF,
                           const float*  __restrict__ lors,
                           float* __restrict__ out, int n, int blk, int ks)
{
    const int tid = threadIdx.x;
    const int lor = blk * LPB + tid;
    const bool active = lor < n;
    const int lorc = active ? lor : n - 1;

    const float* l = lors + (size_t)lorc * 6;
    float l0 = l[0], l1 = l[1], l2 = l[2], l3 = l[3], l4 = l[4], l5 = l[5];
    float p0x, p0y, p0z, p1x, p1y, p1z;
    if (AXIS == 0)      { p0x = l1; p0y = l2; p0z = l0; p1x = l4; p1y = l5; p1z = l3; }
    else if (AXIS == 1) { p0x = l0; p0y = l2; p0z = l1; p1x = l3; p1y = l5; p1z = l4; }
    else                { p0x = l0; p0y = l1; p0z = l2; p1x = l3; p1y = l4; p1z = l5; }

    float dvx = p1x - p0x, dvy = p1y - p0y, dvz = p1z - p0z;
    float L     = sqrtf(dvx * dvx + dvy * dvy + dvz * dvz);
    float pathL = DXC * L / fabsf(dvz);
    float invdz = 1.0f / dvz;

    float dux  = dvx * INV_DX, ux0 = (p0x - XMINC) * INV_DX;
    float dvyS = dvy * INV_DX, vy0 = (p0y - XMINC) * INV_DX;
    float tzs = invdz, tz0 = -p0z * invdz;

    const int k0 = ks * KCH, k1 = k0 + KCH;
    float dt = DXC * tzs;
    float cu = dux * dt, cv = dvyS * dt;
    float zc0 = fmaf((float)k0, DXC, XMINC + 0.5f * DXC);
    float t0  = fmaf(zc0, tzs, tz0);
    float u   = fmaf(t0, dux, ux0);
    float v   = fmaf(t0, dvyS, vy0);
    float acc = 0.0f;

    if (PRE) {
        stage_one(V, k0, tid, sl[k0 & 1]);
    } else {
        float4 st[4];
        stage_issue<AXIS>(imgF, k0, tid, st);
        stage_write(st, sl[k0 & 1], tid);
    }
    {
        float s = ((float)tid + 0.5f) * (4.0f / (float)QTAB);
        float4 e;
        float o0 = 0.5f - s, o1 = 1.5f - s, o2 = 2.5f - s, o3 = 3.5f - s;
        e.x = exp2f(o0 * o0 * NEGL2C);
        e.y = exp2f(o1 * o1 * NEGL2C);
        e.z = exp2f(o2 * o2 * NEGL2C);
        e.w = exp2f(o3 * o3 * NEGL2C);
        wtab[tid] = e;
    }
    __syncthreads();

    for (int k = k0; k < k1; ++k) {
        const ushort* sbuf = sl[k & 1];
        float4 st2[4];
        if (k < k1 - 1) {
            if (PRE) stage_one(V, k + 1, tid, sl[(k & 1) ^ 1]);
            else     stage_issue<AXIS>(imgF, k + 1, tid, st2);
        }

        float e0f = fminf(fmaxf(floorf(v - WOFF), 0.0f), 124.0f);
        int   e0  = (int)e0f;
        int   qv  = min((int)((v - e0f) * (QTAB / 4.0f)), QTAB - 1);
        float4 eb = wtab[qv];
        float db0 = e0f + 0.5f - v;
        float b0 = db0 * db0;
        float gb = fmaf(2.0f, db0, 1.0f);
        float b1 = b0 + gb, gb1 = gb + 2.0f;
        float b2 = b1 + gb1, gb2 = gb1 + 2.0f;
        float b3 = b2 + gb2;

        float i0f = fminf(fmaxf(floorf(u - WOFF), 0.0f), 124.0f);
        int   i0c = (int)i0f;
        int   qu  = min((int)((u - i0f) * (QTAB / 4.0f)), QTAB - 1);
        float4 ea = wtab[qu];
        float da0 = i0f + 0.5f - u;
        float a0 = da0 * da0;
        float ga = fmaf(2.0f, da0, 1.0f);
        float a1 = a0 + ga, ga1 = ga + 2.0f;
        float a2 = a1 + ga1, ga2 = ga1 + 2.0f;
        float a3 = a2 + ga2;
        float thr[4] = {KW2C - a0, KW2C - a1, KW2C - a2, KW2C - a3};
        float eaa[4] = {ea.x, ea.y, ea.z, ea.w};

        const uint* s32 = reinterpret_cast<const uint*>(sbuf);
        int dwc = e0 >> 1;
        int sh  = (e0 & 1) << 4;
        int rowdw = (i0c << 6) + dwc;
#pragma unroll
        for (int r = 0; r < 4; ++r) {
            const uint* sr = s32 + rowdw + (r << 6);
            uint d0 = sr[0], d1 = sr[1], d2 = sr[2];
            uint p01 = __builtin_amdgcn_alignbit(d1, d0, sh);
            uint p23 = __builtin_amdgcn_alignbit(d2, d1, sh);
            float w0 = uaf(p01 << 16);
            float w1 = uaf(p01 & 0xffff0000u);
            float w2 = uaf(p23 << 16);
            float w3 = uaf(p23 & 0xffff0000u);
            float tr = thr[r];
            float rs;
            rs = __fmul_rn((b0 <= tr) ? eb.x : 0.0f, w0);
            rs = fmaf((b1 <= tr) ? eb.y : 0.0f, w1, rs);
            rs = fmaf((b2 <= tr) ? eb.z : 0.0f, w2, rs);
            rs = fmaf((b3 <= tr) ? eb.w : 0.0f, w3, rs);
            acc = fmaf(eaa[r], rs, acc);
        }

        u += cu; v += cv;

        if (k < k1 - 1) {
            if (!PRE) stage_write(st2, sl[(k & 1) ^ 1], tid);
            __syncthreads();
        }
    }

    if (active) atomicAdd(out + lor, acc * pathL);
}

template <bool PRE>
__global__ __launch_bounds__(TPB, 8) void proj_fused7(const float* __restrict__ img,
                                                      const ushort* __restrict__ V0,
                                                      const ushort* __restrict__ V1,
                                                      const ushort* __restrict__ V2,
                                                      const float* __restrict__ xl,
                                                      const float* __restrict__ yl,
                                                      const float* __restrict__ zl,
                                                      float* __restrict__ out,
                                                      int n, int nblk)
{
    __shared__ ushort sl[2][16384];
    __shared__ float4 wtab[QTAB];
    int per = nblk * KSPLIT;
    int axis = blockIdx.x / per;
    int r = blockIdx.x - axis * per;
    int blk = r >> 2;
    int ks  = r & 3;
    if (axis == 0)      proj_axis7<0, PRE>(sl, wtab, V0, img, xl, out, n, blk, ks);
    else if (axis == 1) proj_axis7<1, PRE>(sl, wtab, V1, img, yl, out + n, n, blk, ks);
    else                proj_axis7<2, PRE>(sl, wtab, V2, img, zl, out + 2 * (size_t)n, n, blk, ks);
}

extern "C" void kernel_launch(void* const* d_in, const int* in_sizes, int n_in,
                              void* d_out, int out_size, void* d_ws, size_t ws_size,
                              hipStream_t stream) {
    const float* img   = (const float*)d_in[0];
    const float* xlors = (const float*)d_in[1];
    const float* ylors = (const float*)d_in[2];
    const float* zlors = (const float*)d_in[3];
    float* out = (float*)d_out;

    int n = in_sizes[1] / 6;
    int nblk = (n + LPB - 1) / LPB;
    int m = 3 * n;

    zero_kernel<<<(m + 1023) / 1024, 1024, 0, stream>>>(out, m);

    constexpr size_t VOL = 128 * 128 * 128;
    int grid = 3 * nblk * KSPLIT;

    if (ws_size >= 6 * VOL * sizeof(ushort)) {
        ushort* V0 = (ushort*)d_ws;
        ushort* V1 = V0 + VOL;  ushort* V2 = V1 + VOL;
        ushort* S0 = V2 + VOL;  ushort* S1 = S0 + VOL;  ushort* S2 = S1 + VOL;
        prep2_kernel<<<VOL / 256, 256, 0, stream>>>(img, V0, V1, V2, S0, S1, S2);
        proj_fused8<<<grid, TPB, 0, stream>>>(V0, V1, V2, S0, S1, S2,
                                              xlors, ylors, zlors, out, n, nblk);
    } else if (ws_size >= 3 * VOL * sizeof(ushort)) {
        ushort* V0 = (ushort*)d_ws;
        ushort* V1 = V0 + VOL;  ushort* V2 = V1 + VOL;
        prep_kernel<<<VOL / 256, 256, 0, stream>>>(img, V0, V1, V2);
        proj_fused7<true><<<grid, TPB, 0, stream>>>(img, V0, V1, V2,
                                                    xlors, ylors, zlors, out, n, nblk);
    } else {
        proj_fused7<false><<<grid, TPB, 0, stream>>>(img, nullptr, nullptr, nullptr,
                                                     xlors, ylors, zlors, out, n, nblk);
    }
}